// Round 5
// baseline (72.387 us; speedup 1.0000x reference)
//
#include <hip/hip_runtime.h>
#include <math.h>

#define DIMS 4096
#define NSAMP 1024
#define TPB 256

// native clang vector type — accepted by __builtin_nontemporal_load
typedef float floatx4 __attribute__((ext_vector_type(4)));

// fast softplus: max(x,0) + log(1+exp(-|x|)) with HW exp/log.
// Absolute error contribution ~1e-2 on a ~8500-magnitude result; threshold 137.
__device__ __forceinline__ float fast_softplus(float x) {
    return fmaxf(x, 0.0f) + __logf(1.0f + __expf(-fabsf(x)));
}

// One fused kernel, one sample per block (1024 blocks = 4 blocks/CU,
// 16 waves/CU for memory-level parallelism on the cold theta read).
// Per block accumulate:
//   a1 = sum d^2/c^2, a2 = sum d*b/c^2, beta = sum b^2/c^2, slog = sum log c
// Epilogue (Sherman-Morrison + matrix determinant lemma):
//   quad = a1 - a2^2/(1+beta)
//   out  = -0.5*(quad + D*log2pi + 2*slog + log1p(beta))
__global__ __launch_bounds__(TPB) void nagvac_fused(
        const float* __restrict__ theta,
        const float* __restrict__ mu,
        const float* __restrict__ b,
        const float* __restrict__ log_c,
        float* __restrict__ out) {
    __shared__ float red[4][4];
    const int tid = threadIdx.x;
    const int s   = blockIdx.x;

    const floatx4* th = (const floatx4*)(theta + (size_t)s * DIMS);
    const float4*  m4 = (const float4*)mu;
    const float4*  b4 = (const float4*)b;
    const float4*  l4 = (const float4*)log_c;

    float a1 = 0.f, a2 = 0.f, beta = 0.f, slog = 0.f;

    #pragma unroll
    for (int j = 0; j < DIMS / 4 / TPB; ++j) {
        const int v = j * TPB + tid;
        floatx4 t = __builtin_nontemporal_load(&th[v]);  // streamed, no reuse
        float4 m  = m4[v];
        float4 bv = b4[v];
        float4 lv = l4[v];
        float tt[4] = {t.x, t.y, t.z, t.w};
        float mm[4] = {m.x, m.y, m.z, m.w};
        float bb[4] = {bv.x, bv.y, bv.z, bv.w};
        float ll[4] = {lv.x, lv.y, lv.z, lv.w};
        #pragma unroll
        for (int k = 0; k < 4; ++k) {
            float c  = fast_softplus(ll[k]) + 1e-4f;
            float i2 = __builtin_amdgcn_rcpf(c * c);
            float w  = bb[k] * i2;
            beta += bb[k] * w;
            slog += __logf(c);
            float d = tt[k] - mm[k];
            a1 = fmaf(d * d, i2, a1);
            a2 = fmaf(d, w, a2);
        }
    }

    // 4-value wave64 butterfly, then cross-wave via LDS
    float vals[4] = {a1, a2, beta, slog};
    #pragma unroll
    for (int r = 0; r < 4; ++r) {
        float v = vals[r];
        #pragma unroll
        for (int off = 32; off > 0; off >>= 1) v += __shfl_down(v, off);
        vals[r] = v;
    }
    const int wave = tid >> 6, lane = tid & 63;
    if (lane == 0) {
        #pragma unroll
        for (int r = 0; r < 4; ++r) red[r][wave] = vals[r];
    }
    __syncthreads();

    if (tid == 0) {
        float A1 = red[0][0] + red[0][1] + red[0][2] + red[0][3];
        float A2 = red[1][0] + red[1][1] + red[1][2] + red[1][3];
        float B  = red[2][0] + red[2][1] + red[2][2] + red[2][3];
        float SL = red[3][0] + red[3][1] + red[3][2] + red[3][3];
        float quad = A1 - A2 * A2 / (1.0f + B);
        const float LOG2PI = 1.8378770664093453f;
        out[s] = -0.5f * (quad + (float)DIMS * LOG2PI + 2.0f * SL + log1pf(B));
    }
}

extern "C" void kernel_launch(void* const* d_in, const int* in_sizes, int n_in,
                              void* d_out, int out_size, void* d_ws, size_t ws_size,
                              hipStream_t stream) {
    const float* theta = (const float*)d_in[0];
    const float* mu    = (const float*)d_in[1];
    const float* b     = (const float*)d_in[2];
    const float* log_c = (const float*)d_in[3];
    float* out = (float*)d_out;

    nagvac_fused<<<NSAMP, TPB, 0, stream>>>(theta, mu, b, log_c, out);
}